// Round 1
// baseline (341.111 us; speedup 1.0000x reference)
//
#include <hip/hip_runtime.h>
#include <math.h>

#define H 512
#define W 512
#define HW (H*W)
#define NB 4
#define NC 32

// ---------------- 1x1 conv over channels: sc_raw[b,y,x] = sum_c color*ws[c] ----------------
__global__ __launch_bounds__(256) void k_sc(const float* __restrict__ color,
                                            const float* __restrict__ wscore,
                                            float* __restrict__ sc_raw) {
    int p = blockIdx.x * 256 + threadIdx.x;
    if (p >= NB * HW) return;
    int b = p / HW, i = p % HW;
    const float* base = color + (size_t)b * NC * HW + i;
    float acc = 0.f;
    #pragma unroll
    for (int c = 0; c < NC; ++c) acc += base[(size_t)c * HW] * wscore[c];
    sc_raw[p] = acc;
}

// ---------------- fused avgpool3x3 -> depthwise conv5x5 -> even/odd channel max ----------------
// Each thread: fixed x, strip of 8 consecutive y. Rolling rowsums + 5x5 col window in registers.
__global__ __launch_bounds__(256) void k_whmax(const float* __restrict__ color,
                                               const float* __restrict__ wbbx,
                                               float* __restrict__ wmax_o,
                                               float* __restrict__ hmax_o) {
    const int x  = blockIdx.x * 64 + threadIdx.x;            // blockDim = (64,4)
    const int y0 = (blockIdx.y * 4 + threadIdx.y) * 8;
    const int b  = blockIdx.z;

    float wmx[8], hmx[8];
    #pragma unroll
    for (int t = 0; t < 8; ++t) { wmx[t] = -INFINITY; hmx[t] = -INFINITY; }

    // column validity mask folded with /9
    float cmask[5];
    #pragma unroll
    for (int k = 0; k < 5; ++k) {
        int cx = x - 2 + k;
        cmask[k] = (cx >= 0 && cx < W) ? (1.f / 9.f) : 0.f;
    }

    for (int c = 0; c < NC; ++c) {
        const float* img = color + (size_t)(b * NC + c) * HW;
        const float* wc  = wbbx + c * 25;
        float wr[25];
        #pragma unroll
        for (int k = 0; k < 25; ++k) wr[k] = wc[k];

        float rs2[5], rs1[5], rs0[5];
        float win[25];  // win[i*5+j] = col[y-2+i][x-2+j]

        auto rowsum = [&](int cr, float* rs) {
            if (cr < 0 || cr >= H) {
                #pragma unroll
                for (int k = 0; k < 5; ++k) rs[k] = 0.f;
                return;
            }
            const float* row = img + (size_t)cr * W;
            float v[7];
            #pragma unroll
            for (int k = 0; k < 7; ++k) {
                int cx = x - 3 + k;
                v[k] = (cx >= 0 && cx < W) ? row[cx] : 0.f;
            }
            #pragma unroll
            for (int k = 0; k < 5; ++k) rs[k] = v[k] + v[k + 1] + v[k + 2];
        };
        auto emitcol = [&](int r, const float* a, const float* bb, const float* cc, float* dst) {
            if (r >= 0 && r < H) {
                #pragma unroll
                for (int k = 0; k < 5; ++k) dst[k] = (a[k] + bb[k] + cc[k]) * cmask[k];
            } else {
                #pragma unroll
                for (int k = 0; k < 5; ++k) dst[k] = 0.f;
            }
        };

        rowsum(y0 - 3, rs2);
        rowsum(y0 - 2, rs1);
        #pragma unroll
        for (int i = 0; i < 5; ++i) {       // fill col rows y0-2 .. y0+2
            rowsum(y0 - 1 + i, rs0);
            emitcol(y0 - 2 + i, rs2, rs1, rs0, &win[i * 5]);
            #pragma unroll
            for (int k = 0; k < 5; ++k) { rs2[k] = rs1[k]; rs1[k] = rs0[k]; }
        }

        #pragma unroll
        for (int t = 0; t < 8; ++t) {
            int y = y0 + t;
            float acc = 0.f;
            #pragma unroll
            for (int q = 0; q < 25; ++q) acc += win[q] * wr[q];
            if (c & 1) hmx[t] = fmaxf(hmx[t], acc);
            else       wmx[t] = fmaxf(wmx[t], acc);
            if (t < 7) {
                rowsum(y + 4, rs0);
                #pragma unroll
                for (int q = 0; q < 20; ++q) win[q] = win[q + 5];
                emitcol(y + 3, rs2, rs1, rs0, &win[20]);
                #pragma unroll
                for (int k = 0; k < 5; ++k) { rs2[k] = rs1[k]; rs1[k] = rs0[k]; }
            }
        }
    }
    size_t obase = (size_t)b * HW + (size_t)y0 * W + x;
    #pragma unroll
    for (int t = 0; t < 8; ++t) { wmax_o[obase + t * W] = wmx[t]; hmax_o[obase + t * W] = hmx[t]; }
}

// ---------------- avg pools on score map ----------------
__global__ __launch_bounds__(256) void k_pool5(const float* __restrict__ in, float* __restrict__ out) {
    int p = blockIdx.x * 256 + threadIdx.x;
    if (p >= NB * HW) return;
    int b = p / HW, i = p % HW, y = i / W, x = i % W;
    const float* img = in + (size_t)b * HW;
    float s = 0.f;
    for (int dy = -2; dy <= 2; ++dy) {
        int yy = y + dy; if (yy < 0 || yy >= H) continue;
        for (int dx = -2; dx <= 2; ++dx) {
            int xx = x + dx; if (xx < 0 || xx >= W) continue;
            s += img[yy * W + xx];
        }
    }
    out[p] = s * (1.f / 25.f);
}

__global__ __launch_bounds__(256) void k_pool3(const float* __restrict__ in, float* __restrict__ out) {
    int p = blockIdx.x * 256 + threadIdx.x;
    if (p >= NB * HW) return;
    int b = p / HW, i = p % HW, y = i / W, x = i % W;
    const float* img = in + (size_t)b * HW;
    float s = 0.f;
    for (int dy = -1; dy <= 1; ++dy) {
        int yy = y + dy; if (yy < 0 || yy >= H) continue;
        for (int dx = -1; dx <= 1; ++dx) {
            int xx = x + dx; if (xx < 0 || xx >= W) continue;
            s += img[yy * W + xx];
        }
    }
    out[p] = s * (1.f / 9.f);
}

// ---------------- top-k stage 1: per-block top-10 of s ----------------
__global__ __launch_bounds__(256) void k_cand(const float* __restrict__ sc, float* __restrict__ cand) {
    const int blk = blockIdx.x;   // 32 chunks of 8192
    const int b   = blockIdx.y;
    const int t   = threadIdx.x;
    const float* base = sc + (size_t)b * HW + blk * 8192;

    float top[10];
    #pragma unroll
    for (int k = 0; k < 10; ++k) top[k] = -INFINITY;

    for (int j = t; j < 8192; j += 256) {
        float v = base[j];
        float s = 1.f / (1.f + expf(-v));
        if (s > top[9]) {
            top[9] = s;
            #pragma unroll
            for (int k = 9; k > 0; --k) {
                if (top[k] > top[k - 1]) { float tmp = top[k - 1]; top[k - 1] = top[k]; top[k] = tmp; }
            }
        }
    }

    __shared__ float sv[256];
    __shared__ int   si[256];
    __shared__ int   swin;
    int ptr = 0;
    for (int r = 0; r < 10; ++r) {
        sv[t] = (ptr < 10) ? top[ptr] : -INFINITY;
        si[t] = t;
        __syncthreads();
        for (int off = 128; off > 0; off >>= 1) {
            if (t < off && sv[t + off] > sv[t]) { sv[t] = sv[t + off]; si[t] = si[t + off]; }
            __syncthreads();
        }
        if (t == 0) { cand[((size_t)b * 32 + blk) * 10 + r] = sv[0]; swin = si[0]; }
        __syncthreads();
        if (t == swin) ptr++;
        __syncthreads();
    }
}

// ---------------- top-k stage 2: 10th-largest over 320 candidates (tie-robust rank count) ----------------
__global__ __launch_bounds__(320) void k_v10(const float* __restrict__ cand, float* __restrict__ v10) {
    int b = blockIdx.x, t = threadIdx.x;
    __shared__ float c[320];
    c[t] = cand[b * 320 + t];
    __syncthreads();
    float v = c[t];
    int gt = 0, eq = 0;
    for (int j = 0; j < 320; ++j) { gt += (c[j] > v); eq += (c[j] == v); }
    if (gt <= 9 && gt + eq >= 10) v10[b] = v;
}

// ---------------- final decode ----------------
__global__ __launch_bounds__(256) void k_final(const float* __restrict__ sc,
                                               const float* __restrict__ wm,
                                               const float* __restrict__ hm,
                                               const float* __restrict__ v10,
                                               float* __restrict__ outbuf,
                                               float* __restrict__ mbuf) {
    int p = blockIdx.x * 256 + threadIdx.x;
    if (p >= NB * HW) return;
    int b = p / HW, i = p % HW;
    float scv = sc[p];
    float s   = 1.f / (1.f + expf(-scv));          // same formula as k_cand -> identical bits
    float s10 = v10[b];
    bool  m   = (s >= s10 && s > 0.6f) || (s > 0.9f);
    // NOTE reference quirk: w = channel0 (sc), h = channel1 (wmax)
    float wv = expf(scv) * 10.f;
    float hv = expf(wm[p]) * 10.f;
    float xs = (float)(i & (W - 1));
    float ys = (float)(i >> 9);
    float o0 = 0.f, o1 = 0.f, o2 = 0.f, o3 = 0.f, o4 = 0.f;
    if (m) {
        o0 = s;
        o1 = floorf(xs - wv);
        o2 = floorf(ys - hv);
        o3 = ceilf(xs + wv);
        o4 = ceilf(ys + hv);
    }
    size_t ob = (size_t)p * 5;
    outbuf[ob + 0] = o0; outbuf[ob + 1] = o1; outbuf[ob + 2] = o2;
    outbuf[ob + 3] = o3; outbuf[ob + 4] = o4;
    mbuf[p] = m ? 1.f : 0.f;
}

extern "C" void kernel_launch(void* const* d_in, const int* in_sizes, int n_in,
                              void* d_out, int out_size, void* d_ws, size_t ws_size,
                              hipStream_t stream) {
    // inputs: mask (unused), color, w_bbx, w_score
    const float* color  = (const float*)d_in[1];
    const float* wbbx   = (const float*)d_in[2];
    const float* wscore = (const float*)d_in[3];

    float* out       = (float*)d_out;
    float* score_map = out;                          // 1048576
    float* outbuf    = out + 1048576;                // 5242880
    float* mbuf      = out + 1048576 + 5242880;      // 1048576

    float* ws     = (float*)d_ws;
    float* sc_raw = ws;                  // 1048576 floats
    float* sc1    = ws + 1048576;        // 1048576
    float* wmaxb  = ws + 2 * 1048576;    // 1048576
    float* hmaxb  = ws + 3 * 1048576;    // 1048576
    float* cand   = ws + 4 * 1048576;    // 1280
    float* v10    = cand + 1280;         // 4

    const int npx_blocks = (NB * HW + 255) / 256;    // 4096

    k_sc    <<<npx_blocks, 256, 0, stream>>>(color, wscore, sc_raw);
    k_whmax <<<dim3(8, 16, 4), dim3(64, 4, 1), 0, stream>>>(color, wbbx, wmaxb, hmaxb);
    k_pool5 <<<npx_blocks, 256, 0, stream>>>(sc_raw, sc1);
    k_pool3 <<<npx_blocks, 256, 0, stream>>>(sc1, score_map);
    k_cand  <<<dim3(32, 4), 256, 0, stream>>>(score_map, cand);
    k_v10   <<<4, 320, 0, stream>>>(cand, v10);
    k_final <<<npx_blocks, 256, 0, stream>>>(score_map, wmaxb, hmaxb, v10, outbuf, mbuf);
}

// Round 3
// 212.232 us; speedup vs baseline: 1.6073x; 1.6073x over previous
//
#include <hip/hip_runtime.h>
#include <math.h>

#define H 512
#define W 512
#define HW (H*W)
#define NB 4
#define NC 32

// ---------------- 1x1 conv over channels: sc_raw[b,y,x] = sum_c color*ws[c] ----------------
__global__ __launch_bounds__(256) void k_sc(const float* __restrict__ color,
                                            const float* __restrict__ wscore,
                                            float* __restrict__ sc_raw) {
    int p = blockIdx.x * 256 + threadIdx.x;
    if (p >= NB * HW) return;
    int b = p / HW, i = p % HW;
    const float* base = color + (size_t)b * NC * HW + i;
    float acc = 0.f;
    #pragma unroll
    for (int c = 0; c < NC; ++c) acc += base[(size_t)c * HW] * wscore[c];
    sc_raw[p] = acc;
}

// ---------------- fused avgpool3x3 -> depthwise conv5x5 -> even-channel max ----------------
// Only EVEN channels are ever consumed downstream (h = wmax quirk), so odd channels
// are skipped entirely. Channels split into 2 groups across blockIdx.z for occupancy;
// partial maxes combined in k_final.
__global__ __launch_bounds__(256) void k_whmax(const float* __restrict__ color,
                                               const float* __restrict__ wbbx,
                                               float* __restrict__ pw) {
    const int x  = blockIdx.x * 64 + threadIdx.x;            // blockDim = (64,4)
    const int y0 = (blockIdx.y * 4 + threadIdx.y) * 8;
    const int bz = blockIdx.z;                               // b*2 + g
    const int b  = bz >> 1, g = bz & 1;

    float wmx[8];
    #pragma unroll
    for (int t = 0; t < 8; ++t) wmx[t] = -INFINITY;

    // column validity mask folded with /9
    float cmask[5];
    #pragma unroll
    for (int k = 0; k < 5; ++k) {
        int cx = x - 2 + k;
        cmask[k] = (cx >= 0 && cx < W) ? (1.f / 9.f) : 0.f;
    }

    for (int ci = 0; ci < 8; ++ci) {
        const int c = 2 * (g * 8 + ci);                      // even channels only
        const float* img = color + (size_t)(b * NC + c) * HW;
        const float* wc  = wbbx + c * 25;
        float wr[25];
        #pragma unroll
        for (int k = 0; k < 25; ++k) wr[k] = wc[k];

        float rs2[5], rs1[5], rs0[5];
        float win[25];  // win[i*5+j] = col[y-2+i][x-2+j]

        auto rowsum = [&](int cr, float* rs) {
            if (cr < 0 || cr >= H) {
                #pragma unroll
                for (int k = 0; k < 5; ++k) rs[k] = 0.f;
                return;
            }
            const float* row = img + (size_t)cr * W;
            float v[7];
            #pragma unroll
            for (int k = 0; k < 7; ++k) {
                int cx = x - 3 + k;
                v[k] = (cx >= 0 && cx < W) ? row[cx] : 0.f;
            }
            #pragma unroll
            for (int k = 0; k < 5; ++k) rs[k] = v[k] + v[k + 1] + v[k + 2];
        };
        auto emitcol = [&](int r, const float* a, const float* bb, const float* cc, float* dst) {
            if (r >= 0 && r < H) {
                #pragma unroll
                for (int k = 0; k < 5; ++k) dst[k] = (a[k] + bb[k] + cc[k]) * cmask[k];
            } else {
                #pragma unroll
                for (int k = 0; k < 5; ++k) dst[k] = 0.f;
            }
        };

        rowsum(y0 - 3, rs2);
        rowsum(y0 - 2, rs1);
        #pragma unroll
        for (int i = 0; i < 5; ++i) {       // fill col rows y0-2 .. y0+2
            rowsum(y0 - 1 + i, rs0);
            emitcol(y0 - 2 + i, rs2, rs1, rs0, &win[i * 5]);
            #pragma unroll
            for (int k = 0; k < 5; ++k) { rs2[k] = rs1[k]; rs1[k] = rs0[k]; }
        }

        #pragma unroll
        for (int t = 0; t < 8; ++t) {
            int y = y0 + t;
            float acc = 0.f;
            #pragma unroll
            for (int q = 0; q < 25; ++q) acc += win[q] * wr[q];
            wmx[t] = fmaxf(wmx[t], acc);
            if (t < 7) {
                rowsum(y + 4, rs0);
                #pragma unroll
                for (int q = 0; q < 20; ++q) win[q] = win[q + 5];
                emitcol(y + 3, rs2, rs1, rs0, &win[20]);
                #pragma unroll
                for (int k = 0; k < 5; ++k) { rs2[k] = rs1[k]; rs1[k] = rs0[k]; }
            }
        }
    }
    size_t obase = ((size_t)g * NB + b) * HW + (size_t)y0 * W + x;
    #pragma unroll
    for (int t = 0; t < 8; ++t) pw[obase + t * W] = wmx[t];
}

// ---------------- avg pools on score map ----------------
__global__ __launch_bounds__(256) void k_pool5(const float* __restrict__ in, float* __restrict__ out) {
    int p = blockIdx.x * 256 + threadIdx.x;
    if (p >= NB * HW) return;
    int b = p / HW, i = p % HW, y = i / W, x = i % W;
    const float* img = in + (size_t)b * HW;
    float s = 0.f;
    for (int dy = -2; dy <= 2; ++dy) {
        int yy = y + dy; if (yy < 0 || yy >= H) continue;
        for (int dx = -2; dx <= 2; ++dx) {
            int xx = x + dx; if (xx < 0 || xx >= W) continue;
            s += img[yy * W + xx];
        }
    }
    out[p] = s * (1.f / 25.f);
}

__global__ __launch_bounds__(256) void k_pool3(const float* __restrict__ in, float* __restrict__ out) {
    int p = blockIdx.x * 256 + threadIdx.x;
    if (p >= NB * HW) return;
    int b = p / HW, i = p % HW, y = i / W, x = i % W;
    const float* img = in + (size_t)b * HW;
    float s = 0.f;
    for (int dy = -1; dy <= 1; ++dy) {
        int yy = y + dy; if (yy < 0 || yy >= H) continue;
        for (int dx = -1; dx <= 1; ++dx) {
            int xx = x + dx; if (xx < 0 || xx >= W) continue;
            s += img[yy * W + xx];
        }
    }
    out[p] = s * (1.f / 9.f);
}

// ---------------- top-k stage 1: per-block top-10 of s ----------------
__global__ __launch_bounds__(256) void k_cand(const float* __restrict__ sc, float* __restrict__ cand) {
    const int blk = blockIdx.x;   // 32 chunks of 8192
    const int b   = blockIdx.y;
    const int t   = threadIdx.x;
    const float* base = sc + (size_t)b * HW + blk * 8192;

    float top[10];
    #pragma unroll
    for (int k = 0; k < 10; ++k) top[k] = -INFINITY;

    for (int j = t; j < 8192; j += 256) {
        float v = base[j];
        float s = 1.f / (1.f + expf(-v));
        if (s > top[9]) {
            top[9] = s;
            #pragma unroll
            for (int k = 9; k > 0; --k) {
                if (top[k] > top[k - 1]) { float tmp = top[k - 1]; top[k - 1] = top[k]; top[k] = tmp; }
            }
        }
    }

    __shared__ float sv[256];
    __shared__ int   si[256];
    __shared__ int   swin;
    int ptr = 0;
    for (int r = 0; r < 10; ++r) {
        sv[t] = (ptr < 10) ? top[ptr] : -INFINITY;
        si[t] = t;
        __syncthreads();
        for (int off = 128; off > 0; off >>= 1) {
            if (t < off && sv[t + off] > sv[t]) { sv[t] = sv[t + off]; si[t] = si[t + off]; }
            __syncthreads();
        }
        if (t == 0) { cand[((size_t)b * 32 + blk) * 10 + r] = sv[0]; swin = si[0]; }
        __syncthreads();
        if (t == swin) ptr++;
        __syncthreads();
    }
}

// ---------------- top-k stage 2: 10th-largest over 320 candidates (tie-robust rank count) ----------------
__global__ __launch_bounds__(320) void k_v10(const float* __restrict__ cand, float* __restrict__ v10) {
    int b = blockIdx.x, t = threadIdx.x;
    __shared__ float c[320];
    c[t] = cand[b * 320 + t];
    __syncthreads();
    float v = c[t];
    int gt = 0, eq = 0;
    for (int j = 0; j < 320; ++j) { gt += (c[j] > v); eq += (c[j] == v); }
    if (gt <= 9 && gt + eq >= 10) v10[b] = v;
}

// ---------------- final decode ----------------
__global__ __launch_bounds__(256) void k_final(const float* __restrict__ sc,
                                               const float* __restrict__ pw,
                                               const float* __restrict__ v10,
                                               float* __restrict__ outbuf,
                                               float* __restrict__ mbuf) {
    int p = blockIdx.x * 256 + threadIdx.x;
    if (p >= NB * HW) return;
    int b = p / HW, i = p % HW;
    float scv = sc[p];
    float s   = 1.f / (1.f + expf(-scv));          // same formula as k_cand -> identical bits
    float s10 = v10[b];
    bool  m   = (s >= s10 && s > 0.6f) || (s > 0.9f);
    // reference quirk: w = channel0 (sc), h = channel1 (wmax)
    float wmv = fmaxf(pw[(size_t)b * HW + i], pw[((size_t)NB + b) * HW + i]);
    float wv = expf(scv) * 10.f;
    float hv = expf(wmv) * 10.f;
    float xs = (float)(i & (W - 1));
    float ys = (float)(i >> 9);
    float o0 = 0.f, o1 = 0.f, o2 = 0.f, o3 = 0.f, o4 = 0.f;
    if (m) {
        o0 = s;
        o1 = floorf(xs - wv);
        o2 = floorf(ys - hv);
        o3 = ceilf(xs + wv);
        o4 = ceilf(ys + hv);
    }
    size_t ob = (size_t)p * 5;
    outbuf[ob + 0] = o0; outbuf[ob + 1] = o1; outbuf[ob + 2] = o2;
    outbuf[ob + 3] = o3; outbuf[ob + 4] = o4;
    mbuf[p] = m ? 1.f : 0.f;
}

extern "C" void kernel_launch(void* const* d_in, const int* in_sizes, int n_in,
                              void* d_out, int out_size, void* d_ws, size_t ws_size,
                              hipStream_t stream) {
    // inputs: mask (unused), color, w_bbx, w_score
    const float* color  = (const float*)d_in[1];
    const float* wbbx   = (const float*)d_in[2];
    const float* wscore = (const float*)d_in[3];

    float* out       = (float*)d_out;
    float* score_map = out;                          // 1048576
    float* outbuf    = out + 1048576;                // 5242880
    float* mbuf      = out + 1048576 + 5242880;      // 1048576

    float* ws     = (float*)d_ws;
    float* sc_raw = ws;                  // 1048576 floats
    float* sc1    = ws + 1048576;        // 1048576
    float* pw     = ws + 2 * 1048576;    // 2 groups x 4*HW = 2097152
    float* cand   = ws + 4 * 1048576;    // 1280
    float* v10    = cand + 1280;         // 4

    const int npx_blocks = (NB * HW + 255) / 256;    // 4096

    k_sc    <<<npx_blocks, 256, 0, stream>>>(color, wscore, sc_raw);
    k_whmax <<<dim3(8, 16, NB * 2), dim3(64, 4, 1), 0, stream>>>(color, wbbx, pw);
    k_pool5 <<<npx_blocks, 256, 0, stream>>>(sc_raw, sc1);
    k_pool3 <<<npx_blocks, 256, 0, stream>>>(sc1, score_map);
    k_cand  <<<dim3(32, 4), 256, 0, stream>>>(score_map, cand);
    k_v10   <<<4, 320, 0, stream>>>(cand, v10);
    k_final <<<npx_blocks, 256, 0, stream>>>(score_map, pw, v10, outbuf, mbuf);
}

// Round 4
// 142.444 us; speedup vs baseline: 2.3947x; 1.4899x over previous
//
#include <hip/hip_runtime.h>
#include <math.h>

#define H 512
#define W 512
#define HW (H*W)
#define NB 4
#define NC 32

// ---------------- 1x1 conv over channels, float4-vectorized ----------------
__global__ __launch_bounds__(256) void k_sc(const float* __restrict__ color,
                                            const float* __restrict__ wscore,
                                            float* __restrict__ sc_raw) {
    int p4 = blockIdx.x * 256 + threadIdx.x;
    const int NP4 = NB * HW / 4;
    if (p4 >= NP4) return;
    int b = p4 / (HW / 4), i4 = p4 % (HW / 4);
    const float4* base = (const float4*)(color + (size_t)b * NC * HW) + i4;
    float4 acc = make_float4(0.f, 0.f, 0.f, 0.f);
    #pragma unroll
    for (int c = 0; c < NC; ++c) {
        float4 v = base[(size_t)c * (HW / 4)];
        float wv = wscore[c];
        acc.x = fmaf(v.x, wv, acc.x);
        acc.y = fmaf(v.y, wv, acc.y);
        acc.z = fmaf(v.z, wv, acc.z);
        acc.w = fmaf(v.w, wv, acc.w);
    }
    ((float4*)sc_raw)[p4] = acc;
}

// ---------------- fused avgpool3x3 -> depthwise conv5x5 -> even-channel max ----------------
// 4x4 output tile per thread, float4 global loads, streaming accumulation
// (each pooled row feeds its <=4 consumer output rows immediately; no window regs).
// Odd channels are dead code downstream (h = wmax quirk). 2 channel groups via blockIdx.z.
__global__ __launch_bounds__(256) void k_whmax(const float* __restrict__ color,
                                               const float* __restrict__ wbbx,
                                               float* __restrict__ pw) {
    const int lane = threadIdx.x;                           // blockDim = (64,4)
    const int x0 = (blockIdx.x * 64 + lane) * 4;            // 0..508, multiple of 4
    const int y0 = (blockIdx.y * 4 + threadIdx.y) * 4;      // 0..508
    const int bz = blockIdx.z;                              // b*2 + g
    const int b = bz >> 1, g = bz & 1;

    const bool m0 = (x0 >= 4);          // left float4 chunk fully valid?
    const bool m2 = (x0 <= 504);        // right float4 chunk fully valid?
    const int xm4 = m0 ? (x0 - 4) : x0; // safe addresses (value masked below)
    const int xp4 = m2 ? (x0 + 4) : x0;

    float colmask[8];                   // pooled-column validity (conv zero-padding in x) * 1/9
    #pragma unroll
    for (int j = 0; j < 8; ++j) {
        int cxx = x0 - 2 + j;
        colmask[j] = (cxx >= 0 && cxx < W) ? (1.f / 9.f) : 0.f;
    }

    float wmx[4][4];
    #pragma unroll
    for (int ot = 0; ot < 4; ++ot)
        #pragma unroll
        for (int oc = 0; oc < 4; ++oc) wmx[ot][oc] = -INFINITY;

    for (int ci = 0; ci < 8; ++ci) {
        const int c = 2 * (g * 8 + ci);                      // even channels only
        const float* img = color + (size_t)(b * NC + c) * HW;
        const float* wc  = wbbx + c * 25;

        float acc[4][4];
        #pragma unroll
        for (int ot = 0; ot < 4; ++ot)
            #pragma unroll
            for (int oc = 0; oc < 4; ++oc) acc[ot][oc] = 0.f;

        float rs[3][8];   // rolling 3x3-rowsums at pooled cols x0-2..x0+5

        auto loadrs = [&](int r, float* dst) {
            if (r < 0 || r >= H) {                           // wave-uniform branch
                #pragma unroll
                for (int j = 0; j < 8; ++j) dst[j] = 0.f;
                return;
            }
            const float* row = img + (size_t)r * W;
            float4 c0 = *(const float4*)(row + xm4);
            float4 c1 = *(const float4*)(row + x0);
            float4 c2 = *(const float4*)(row + xp4);
            if (!m0) c0 = make_float4(0.f, 0.f, 0.f, 0.f);
            if (!m2) c2 = make_float4(0.f, 0.f, 0.f, 0.f);
            float v[12];
            v[0] = c0.x; v[1] = c0.y; v[2]  = c0.z; v[3]  = c0.w;
            v[4] = c1.x; v[5] = c1.y; v[6]  = c1.z; v[7]  = c1.w;
            v[8] = c2.x; v[9] = c2.y; v[10] = c2.z; v[11] = c2.w;
            #pragma unroll
            for (int j = 0; j < 8; ++j) dst[j] = v[j + 1] + v[j + 2] + v[j + 3];
        };

        loadrs(y0 - 3, rs[0]);
        loadrs(y0 - 2, rs[1]);

        #pragma unroll
        for (int it = 0; it < 8; ++it) {                     // col rows y0-2 .. y0+5
            const int sA = it % 3, sB = (it + 1) % 3, sC = (it + 2) % 3;
            loadrs(y0 - 1 + it, rs[sC]);
            const int cr = y0 - 2 + it;
            float col[8];
            if (cr >= 0 && cr < H) {                         // wave-uniform
                #pragma unroll
                for (int j = 0; j < 8; ++j)
                    col[j] = (rs[sA][j] + rs[sB][j] + rs[sC][j]) * colmask[j];
            } else {
                #pragma unroll
                for (int j = 0; j < 8; ++j) col[j] = 0.f;
            }
            #pragma unroll
            for (int ot = 0; ot < 4; ++ot) {
                if (ot >= it - 4 && ot <= it) {              // compile-time after unroll
                    const int kr = it - ot;                  // weight row
                    #pragma unroll
                    for (int oc = 0; oc < 4; ++oc) {
                        float a = acc[ot][oc];
                        #pragma unroll
                        for (int d = 0; d < 5; ++d)
                            a = fmaf(col[oc + d], wc[kr * 5 + d], a);
                        acc[ot][oc] = a;
                    }
                }
            }
        }

        #pragma unroll
        for (int ot = 0; ot < 4; ++ot)
            #pragma unroll
            for (int oc = 0; oc < 4; ++oc)
                wmx[ot][oc] = fmaxf(wmx[ot][oc], acc[ot][oc]);
    }

    float* obase = pw + ((size_t)g * NB + b) * HW + (size_t)y0 * W + x0;
    #pragma unroll
    for (int ot = 0; ot < 4; ++ot) {
        float4 o = make_float4(wmx[ot][0], wmx[ot][1], wmx[ot][2], wmx[ot][3]);
        *(float4*)(obase + (size_t)ot * W) = o;
    }
}

// ---------------- avg pools on score map ----------------
__global__ __launch_bounds__(256) void k_pool5(const float* __restrict__ in, float* __restrict__ out) {
    int p = blockIdx.x * 256 + threadIdx.x;
    if (p >= NB * HW) return;
    int b = p / HW, i = p % HW, y = i / W, x = i % W;
    const float* img = in + (size_t)b * HW;
    float s = 0.f;
    for (int dy = -2; dy <= 2; ++dy) {
        int yy = y + dy; if (yy < 0 || yy >= H) continue;
        for (int dx = -2; dx <= 2; ++dx) {
            int xx = x + dx; if (xx < 0 || xx >= W) continue;
            s += img[yy * W + xx];
        }
    }
    out[p] = s * (1.f / 25.f);
}

__global__ __launch_bounds__(256) void k_pool3(const float* __restrict__ in, float* __restrict__ out) {
    int p = blockIdx.x * 256 + threadIdx.x;
    if (p >= NB * HW) return;
    int b = p / HW, i = p % HW, y = i / W, x = i % W;
    const float* img = in + (size_t)b * HW;
    float s = 0.f;
    for (int dy = -1; dy <= 1; ++dy) {
        int yy = y + dy; if (yy < 0 || yy >= H) continue;
        for (int dx = -1; dx <= 1; ++dx) {
            int xx = x + dx; if (xx < 0 || xx >= W) continue;
            s += img[yy * W + xx];
        }
    }
    out[p] = s * (1.f / 9.f);
}

// ---------------- top-k stage 1: per-block top-10 of s ----------------
__global__ __launch_bounds__(256) void k_cand(const float* __restrict__ sc, float* __restrict__ cand) {
    const int blk = blockIdx.x;   // 32 chunks of 8192
    const int b   = blockIdx.y;
    const int t   = threadIdx.x;
    const float* base = sc + (size_t)b * HW + blk * 8192;

    float top[10];
    #pragma unroll
    for (int k = 0; k < 10; ++k) top[k] = -INFINITY;

    for (int j = t; j < 8192; j += 256) {
        float v = base[j];
        float s = 1.f / (1.f + expf(-v));
        if (s > top[9]) {
            top[9] = s;
            #pragma unroll
            for (int k = 9; k > 0; --k) {
                if (top[k] > top[k - 1]) { float tmp = top[k - 1]; top[k - 1] = top[k]; top[k] = tmp; }
            }
        }
    }

    __shared__ float sv[256];
    __shared__ int   si[256];
    __shared__ int   swin;
    int ptr = 0;
    for (int r = 0; r < 10; ++r) {
        sv[t] = (ptr < 10) ? top[ptr] : -INFINITY;
        si[t] = t;
        __syncthreads();
        for (int off = 128; off > 0; off >>= 1) {
            if (t < off && sv[t + off] > sv[t]) { sv[t] = sv[t + off]; si[t] = si[t + off]; }
            __syncthreads();
        }
        if (t == 0) { cand[((size_t)b * 32 + blk) * 10 + r] = sv[0]; swin = si[0]; }
        __syncthreads();
        if (t == swin) ptr++;
        __syncthreads();
    }
}

// ---------------- top-k stage 2: 10th-largest over 320 candidates ----------------
__global__ __launch_bounds__(320) void k_v10(const float* __restrict__ cand, float* __restrict__ v10) {
    int b = blockIdx.x, t = threadIdx.x;
    __shared__ float c[320];
    c[t] = cand[b * 320 + t];
    __syncthreads();
    float v = c[t];
    int gt = 0, eq = 0;
    for (int j = 0; j < 320; ++j) { gt += (c[j] > v); eq += (c[j] == v); }
    if (gt <= 9 && gt + eq >= 10) v10[b] = v;
}

// ---------------- final decode ----------------
__global__ __launch_bounds__(256) void k_final(const float* __restrict__ sc,
                                               const float* __restrict__ pw,
                                               const float* __restrict__ v10,
                                               float* __restrict__ outbuf,
                                               float* __restrict__ mbuf) {
    int p = blockIdx.x * 256 + threadIdx.x;
    if (p >= NB * HW) return;
    int b = p / HW, i = p % HW;
    float scv = sc[p];
    float s   = 1.f / (1.f + expf(-scv));          // same formula as k_cand -> identical bits
    float s10 = v10[b];
    bool  m   = (s >= s10 && s > 0.6f) || (s > 0.9f);
    // reference quirk: w = channel0 (sc), h = channel1 (wmax)
    float wmv = fmaxf(pw[(size_t)b * HW + i], pw[((size_t)NB + b) * HW + i]);
    float wv = expf(scv) * 10.f;
    float hv = expf(wmv) * 10.f;
    float xs = (float)(i & (W - 1));
    float ys = (float)(i >> 9);
    float o0 = 0.f, o1 = 0.f, o2 = 0.f, o3 = 0.f, o4 = 0.f;
    if (m) {
        o0 = s;
        o1 = floorf(xs - wv);
        o2 = floorf(ys - hv);
        o3 = ceilf(xs + wv);
        o4 = ceilf(ys + hv);
    }
    size_t ob = (size_t)p * 5;
    outbuf[ob + 0] = o0; outbuf[ob + 1] = o1; outbuf[ob + 2] = o2;
    outbuf[ob + 3] = o3; outbuf[ob + 4] = o4;
    mbuf[p] = m ? 1.f : 0.f;
}

extern "C" void kernel_launch(void* const* d_in, const int* in_sizes, int n_in,
                              void* d_out, int out_size, void* d_ws, size_t ws_size,
                              hipStream_t stream) {
    // inputs: mask (unused), color, w_bbx, w_score
    const float* color  = (const float*)d_in[1];
    const float* wbbx   = (const float*)d_in[2];
    const float* wscore = (const float*)d_in[3];

    float* out       = (float*)d_out;
    float* score_map = out;                          // 1048576
    float* outbuf    = out + 1048576;                // 5242880
    float* mbuf      = out + 1048576 + 5242880;      // 1048576

    float* ws     = (float*)d_ws;
    float* sc_raw = ws;                  // 1048576 floats
    float* sc1    = ws + 1048576;        // 1048576
    float* pw     = ws + 2 * 1048576;    // 2 groups x 4*HW = 2097152
    float* cand   = ws + 4 * 1048576;    // 1280
    float* v10    = cand + 1280;         // 4

    const int npx_blocks = (NB * HW + 255) / 256;    // 4096

    k_sc    <<<(NB * HW / 4 + 255) / 256, 256, 0, stream>>>(color, wscore, sc_raw);
    k_whmax <<<dim3(2, 32, NB * 2), dim3(64, 4, 1), 0, stream>>>(color, wbbx, pw);
    k_pool5 <<<npx_blocks, 256, 0, stream>>>(sc_raw, sc1);
    k_pool3 <<<npx_blocks, 256, 0, stream>>>(sc1, score_map);
    k_cand  <<<dim3(32, 4), 256, 0, stream>>>(score_map, cand);
    k_v10   <<<4, 320, 0, stream>>>(cand, v10);
    k_final <<<npx_blocks, 256, 0, stream>>>(score_map, pw, v10, outbuf, mbuf);
}

// Round 6
// 139.567 us; speedup vs baseline: 2.4441x; 1.0206x over previous
//
#include <hip/hip_runtime.h>
#include <math.h>

#define H 512
#define W 512
#define HW (H*W)
#define NB 4
#define NC 32

// ---------------- 1x1 conv over ODD channels only, float4 ----------------
// (even-channel contribution is accumulated inside k_whmax while it has the data)
__global__ __launch_bounds__(256) void k_sc_odd(const float* __restrict__ color,
                                                const float* __restrict__ wscore,
                                                float* __restrict__ scO) {
    int p4 = blockIdx.x * 256 + threadIdx.x;
    const int NP4 = NB * HW / 4;
    if (p4 >= NP4) return;
    int b = p4 / (HW / 4), i4 = p4 % (HW / 4);
    const float4* base = (const float4*)(color + (size_t)b * NC * HW) + i4;
    float4 acc = make_float4(0.f, 0.f, 0.f, 0.f);
    #pragma unroll
    for (int ci = 0; ci < 16; ++ci) {
        const int c = 2 * ci + 1;
        float4 v = base[(size_t)c * (HW / 4)];
        float wv = wscore[c];
        acc.x = fmaf(v.x, wv, acc.x);
        acc.y = fmaf(v.y, wv, acc.y);
        acc.z = fmaf(v.z, wv, acc.z);
        acc.w = fmaf(v.w, wv, acc.w);
    }
    ((float4*)scO)[p4] = acc;
}

// ---------------- fused avgpool3x3 -> depthwise conv5x5 -> even-channel max ----------------
// Also accumulates the even-channel half of the 1x1 score conv (center rows are
// already in registers). Odd conv channels are dead code downstream (h = wmax quirk).
__global__ __launch_bounds__(256) void k_whmax(const float* __restrict__ color,
                                               const float* __restrict__ wbbx,
                                               const float* __restrict__ wscore,
                                               float* __restrict__ pw,
                                               float* __restrict__ scE) {
    const int lane = threadIdx.x;                           // blockDim = (64,4)
    const int x0 = (blockIdx.x * 64 + lane) * 4;            // 0..508, multiple of 4
    const int y0 = (blockIdx.y * 4 + threadIdx.y) * 4;      // 0..508
    const int bz = blockIdx.z;                              // b*2 + g
    const int b = bz >> 1, g = bz & 1;

    const bool m0 = (x0 >= 4);          // left float4 chunk fully valid?
    const bool m2 = (x0 <= 504);        // right float4 chunk fully valid?
    const int xm4 = m0 ? (x0 - 4) : x0;
    const int xp4 = m2 ? (x0 + 4) : x0;

    float colmask[8];                   // pooled-column validity * 1/9
    #pragma unroll
    for (int j = 0; j < 8; ++j) {
        int cxx = x0 - 2 + j;
        colmask[j] = (cxx >= 0 && cxx < W) ? (1.f / 9.f) : 0.f;
    }

    float wmx[4][4], scacc[4][4];
    #pragma unroll
    for (int ot = 0; ot < 4; ++ot)
        #pragma unroll
        for (int oc = 0; oc < 4; ++oc) { wmx[ot][oc] = -INFINITY; scacc[ot][oc] = 0.f; }

    for (int ci = 0; ci < 8; ++ci) {
        const int c = 2 * (g * 8 + ci);                      // even channels only
        const float* img = color + (size_t)(b * NC + c) * HW;
        const float* wc  = wbbx + c * 25;
        const float wsc  = wscore[c];

        float acc[4][4];
        #pragma unroll
        for (int ot = 0; ot < 4; ++ot)
            #pragma unroll
            for (int oc = 0; oc < 4; ++oc) acc[ot][oc] = 0.f;

        float rs[3][8];   // rolling 3x3-rowsums at pooled cols x0-2..x0+5

        auto loadrs = [&](int r, float* dst, int cot) {
            if (r < 0 || r >= H) {                           // wave-uniform branch
                #pragma unroll
                for (int j = 0; j < 8; ++j) dst[j] = 0.f;
                return;
            }
            const float* row = img + (size_t)r * W;
            float4 c0 = *(const float4*)(row + xm4);
            float4 c1 = *(const float4*)(row + x0);
            float4 c2 = *(const float4*)(row + xp4);
            if (!m0) c0 = make_float4(0.f, 0.f, 0.f, 0.f);
            if (!m2) c2 = make_float4(0.f, 0.f, 0.f, 0.f);
            if (cot >= 0) {                                  // compile-time after unroll
                scacc[cot][0] = fmaf(c1.x, wsc, scacc[cot][0]);
                scacc[cot][1] = fmaf(c1.y, wsc, scacc[cot][1]);
                scacc[cot][2] = fmaf(c1.z, wsc, scacc[cot][2]);
                scacc[cot][3] = fmaf(c1.w, wsc, scacc[cot][3]);
            }
            float v[12];
            v[0] = c0.x; v[1] = c0.y; v[2]  = c0.z; v[3]  = c0.w;
            v[4] = c1.x; v[5] = c1.y; v[6]  = c1.z; v[7]  = c1.w;
            v[8] = c2.x; v[9] = c2.y; v[10] = c2.z; v[11] = c2.w;
            #pragma unroll
            for (int j = 0; j < 8; ++j) dst[j] = v[j + 1] + v[j + 2] + v[j + 3];
        };

        loadrs(y0 - 3, rs[0], -1);
        loadrs(y0 - 2, rs[1], -1);

        #pragma unroll
        for (int it = 0; it < 8; ++it) {                     // pooled rows y0-2 .. y0+5
            const int sA = it % 3, sB = (it + 1) % 3, sC = (it + 2) % 3;
            loadrs(y0 - 1 + it, rs[sC], (it >= 1 && it <= 4) ? it - 1 : -1);
            const int cr = y0 - 2 + it;
            float col[8];
            if (cr >= 0 && cr < H) {                         // wave-uniform
                #pragma unroll
                for (int j = 0; j < 8; ++j)
                    col[j] = (rs[sA][j] + rs[sB][j] + rs[sC][j]) * colmask[j];
            } else {
                #pragma unroll
                for (int j = 0; j < 8; ++j) col[j] = 0.f;
            }
            #pragma unroll
            for (int ot = 0; ot < 4; ++ot) {
                if (ot >= it - 4 && ot <= it) {              // compile-time after unroll
                    const int kr = it - ot;                  // weight row
                    #pragma unroll
                    for (int oc = 0; oc < 4; ++oc) {
                        float a = acc[ot][oc];
                        #pragma unroll
                        for (int d = 0; d < 5; ++d)
                            a = fmaf(col[oc + d], wc[kr * 5 + d], a);
                        acc[ot][oc] = a;
                    }
                }
            }
        }

        #pragma unroll
        for (int ot = 0; ot < 4; ++ot)
            #pragma unroll
            for (int oc = 0; oc < 4; ++oc)
                wmx[ot][oc] = fmaxf(wmx[ot][oc], acc[ot][oc]);
    }

    size_t off = ((size_t)g * NB + b) * HW + (size_t)y0 * W + x0;
    #pragma unroll
    for (int ot = 0; ot < 4; ++ot) {
        *(float4*)(pw + off + (size_t)ot * W)  = make_float4(wmx[ot][0], wmx[ot][1], wmx[ot][2], wmx[ot][3]);
        *(float4*)(scE + off + (size_t)ot * W) = make_float4(scacc[ot][0], scacc[ot][1], scacc[ot][2], scacc[ot][3]);
    }
}

// ---------------- fused: sum sc partials -> avgpool5 -> avgpool3 -> sigmoid+top10 ----------------
// One 8-row x 512-col output stripe per block. Separable box sums in LDS.
__global__ __launch_bounds__(256) void k_poolcand(const float* __restrict__ scE,
                                                  const float* __restrict__ scO,
                                                  float* __restrict__ score_map,
                                                  float* __restrict__ cand) {
    const int sb = blockIdx.x;           // 0..63  (stripe)
    const int b  = blockIdx.y;
    const int t  = threadIdx.x;
    const int y0 = sb * 8;

    __shared__ float A[14][512];         // sc rows y0-3..y0+10, later P5 rows y0-1..y0+8
    __shared__ float Bf[14][512];        // T1 rows,            later T2 rows

    // load sc = scE0 + scE1 + scO (zero outside)
    for (int r = 0; r < 14; ++r) {
        int gy = y0 - 3 + r;
        for (int xx = t; xx < 512; xx += 256) {
            float v = 0.f;
            if (gy >= 0 && gy < H) {
                size_t idx = (size_t)b * HW + (size_t)gy * W + xx;
                v = scE[idx] + scE[(size_t)NB * HW + idx] + scO[idx];
            }
            A[r][xx] = v;
        }
    }
    __syncthreads();
    // T1 = rowsum5(sc), x zero-pad
    for (int r = 0; r < 14; ++r)
        for (int xx = t; xx < 512; xx += 256) {
            float s = 0.f;
            #pragma unroll
            for (int d = -2; d <= 2; ++d) {
                int x2 = xx + d;
                if (x2 >= 0 && x2 < 512) s += A[r][x2];
            }
            Bf[r][xx] = s;
        }
    __syncthreads();
    // P5 rows y0-1..y0+8 (zero row if OOB) -> A[0..9]
    for (int r2 = 0; r2 < 10; ++r2) {
        int gy = y0 - 1 + r2;
        for (int xx = t; xx < 512; xx += 256) {
            float s = 0.f;
            if (gy >= 0 && gy < H) {
                #pragma unroll
                for (int d = 0; d < 5; ++d) s += Bf[r2 + d][xx];
                s *= (1.f / 25.f);
            }
            A[r2][xx] = s;
        }
    }
    __syncthreads();
    // T2 = rowsum3(P5), x zero-pad -> Bf[0..9]
    for (int r2 = 0; r2 < 10; ++r2)
        for (int xx = t; xx < 512; xx += 256) {
            float s = 0.f;
            #pragma unroll
            for (int d = -1; d <= 1; ++d) {
                int x2 = xx + d;
                if (x2 >= 0 && x2 < 512) s += A[r2][x2];
            }
            Bf[r2][xx] = s;
        }
    __syncthreads();

    // score rows y0..y0+7 = colsum3(T2)/9 ; write + sigmoid + thread top-10
    float top[10];
    #pragma unroll
    for (int k = 0; k < 10; ++k) top[k] = -INFINITY;

    for (int r3 = 0; r3 < 8; ++r3) {
        for (int xx = t; xx < 512; xx += 256) {
            float sv = (Bf[r3][xx] + Bf[r3 + 1][xx] + Bf[r3 + 2][xx]) * (1.f / 9.f);
            score_map[(size_t)b * HW + (size_t)(y0 + r3) * W + xx] = sv;
            float s = 1.f / (1.f + expf(-sv));
            if (s > top[9]) {
                top[9] = s;
                #pragma unroll
                for (int k = 9; k > 0; --k)
                    if (top[k] > top[k - 1]) { float tmp = top[k - 1]; top[k - 1] = top[k]; top[k] = tmp; }
            }
        }
    }

    // block top-10 reduction
    __shared__ float sv_[256];
    __shared__ int   si_[256];
    __shared__ int   swin;
    int ptr = 0;
    for (int r = 0; r < 10; ++r) {
        sv_[t] = (ptr < 10) ? top[ptr] : -INFINITY;
        si_[t] = t;
        __syncthreads();
        for (int off = 128; off > 0; off >>= 1) {
            if (t < off && sv_[t + off] > sv_[t]) { sv_[t] = sv_[t + off]; si_[t] = si_[t + off]; }
            __syncthreads();
        }
        if (t == 0) { cand[((size_t)b * 64 + sb) * 10 + r] = sv_[0]; swin = si_[0]; }
        __syncthreads();
        if (t == swin) ptr++;
        __syncthreads();
    }
}

// ---------------- 10th-largest over 640 candidates (tie-robust rank count) ----------------
__global__ __launch_bounds__(256) void k_v10(const float* __restrict__ cand, float* __restrict__ v10) {
    int b = blockIdx.x, t = threadIdx.x;
    __shared__ float c[640];
    for (int j = t; j < 640; j += 256) c[j] = cand[b * 640 + j];
    __syncthreads();
    for (int j = t; j < 640; j += 256) {
        float v = c[j];
        int gt = 0, eq = 0;
        for (int k = 0; k < 640; ++k) { gt += (c[k] > v); eq += (c[k] == v); }
        if (gt <= 9 && gt + eq >= 10) v10[b] = v;
    }
}

// ---------------- final decode ----------------
__global__ __launch_bounds__(256) void k_final(const float* __restrict__ sc,
                                               const float* __restrict__ pw,
                                               const float* __restrict__ v10,
                                               float* __restrict__ outbuf,
                                               float* __restrict__ mbuf) {
    int p = blockIdx.x * 256 + threadIdx.x;
    if (p >= NB * HW) return;
    int b = p / HW, i = p % HW;
    float scv = sc[p];
    float s   = 1.f / (1.f + expf(-scv));          // same formula as k_poolcand -> identical bits
    float s10 = v10[b];
    bool  m   = (s >= s10 && s > 0.6f) || (s > 0.9f);
    // reference quirk: w = channel0 (sc), h = channel1 (wmax)
    float wmv = fmaxf(pw[(size_t)b * HW + i], pw[((size_t)NB + b) * HW + i]);
    float wv = expf(scv) * 10.f;
    float hv = expf(wmv) * 10.f;
    float xs = (float)(i & (W - 1));
    float ys = (float)(i >> 9);
    float o0 = 0.f, o1 = 0.f, o2 = 0.f, o3 = 0.f, o4 = 0.f;
    if (m) {
        o0 = s;
        o1 = floorf(xs - wv);
        o2 = floorf(ys - hv);
        o3 = ceilf(xs + wv);
        o4 = ceilf(ys + hv);
    }
    size_t ob = (size_t)p * 5;
    outbuf[ob + 0] = o0; outbuf[ob + 1] = o1; outbuf[ob + 2] = o2;
    outbuf[ob + 3] = o3; outbuf[ob + 4] = o4;
    mbuf[p] = m ? 1.f : 0.f;
}

extern "C" void kernel_launch(void* const* d_in, const int* in_sizes, int n_in,
                              void* d_out, int out_size, void* d_ws, size_t ws_size,
                              hipStream_t stream) {
    // inputs: mask (unused), color, w_bbx, w_score
    const float* color  = (const float*)d_in[1];
    const float* wbbx   = (const float*)d_in[2];
    const float* wscore = (const float*)d_in[3];

    float* out       = (float*)d_out;
    float* score_map = out;                          // 1048576
    float* outbuf    = out + 1048576;                // 5242880
    float* mbuf      = out + 1048576 + 5242880;      // 1048576

    float* ws   = (float*)d_ws;
    float* pw   = ws;                      // 2 * NB*HW = 2097152
    float* scE  = ws + 2 * 1048576;        // 2 * NB*HW = 2097152
    float* scO  = ws + 4 * 1048576;        // NB*HW    = 1048576
    float* cand = ws + 5 * 1048576;        // 4*640 = 2560
    float* v10  = cand + 2560;             // 4

    k_whmax    <<<dim3(2, 32, NB * 2), dim3(64, 4, 1), 0, stream>>>(color, wbbx, wscore, pw, scE);
    k_sc_odd   <<<(NB * HW / 4 + 255) / 256, 256, 0, stream>>>(color, wscore, scO);
    k_poolcand <<<dim3(64, NB), 256, 0, stream>>>(scE, scO, score_map, cand);
    k_v10      <<<4, 256, 0, stream>>>(cand, v10);
    k_final    <<<(NB * HW + 255) / 256, 256, 0, stream>>>(score_map, pw, v10, outbuf, mbuf);
}